// Round 14
// baseline (486.381 us; speedup 1.0000x reference)
//
#include <hip/hip_runtime.h>

#define Hd 256
#define NNODE 10000
#define NE1 131072
#define NE2 65536
#define TROWS 4097
#define TLD 1792     // 7 * 256 packed table columns

typedef __attribute__((ext_vector_type(8))) short bf16x8;
typedef __attribute__((ext_vector_type(4))) float f32x4;

#define MFMA16(a, b, c) __builtin_amdgcn_mfma_f32_16x16x32_bf16((a), (b), (c), 0, 0, 0)

__device__ __forceinline__ float b2f(ushort u) { return __uint_as_float(((unsigned)u) << 16); }
__device__ __forceinline__ ushort f2b(float f) {
  unsigned u = __float_as_uint(f);
  return (ushort)((u + 0x7fffu + ((u >> 16) & 1u)) >> 16);
}

// async global->LDS 16B (dest = wave-uniform base + lane*16; global src per-lane)
__device__ __forceinline__ void gload16(const ushort* g, ushort* l) {
  __builtin_amdgcn_global_load_lds(
      (const __attribute__((address_space(1))) unsigned int*)g,
      (__attribute__((address_space(3))) unsigned int*)l, 16, 0, 0);
}

// combine two packed bf16 lanes: relu(a + b + t), repack (identical math to scalar path)
__device__ __forceinline__ unsigned comb2(unsigned a, unsigned b, unsigned t) {
  float alo = __uint_as_float(a << 16), ahi = __uint_as_float(a & 0xffff0000u);
  float blo = __uint_as_float(b << 16), bhi = __uint_as_float(b & 0xffff0000u);
  float tlo = __uint_as_float(t << 16), thi = __uint_as_float(t & 0xffff0000u);
  float zlo = fmaxf(alo + blo + tlo, 0.f);
  float zhi = fmaxf(ahi + bhi + thi, 0.f);
  return ((unsigned)f2b(zhi) << 16) | (unsigned)f2b(zlo);
}

// ---------------- small kernels ----------------

__global__ void time_mlp_k(const float* __restrict__ tval,
                           const float* __restrict__ W0, const float* __restrict__ b0,
                           const float* __restrict__ W1, const float* __restrict__ b1,
                           const float* __restrict__ W2, const float* __restrict__ b2,
                           float* __restrict__ tenc) {
  __shared__ float h0[Hd], h1[Hd];
  int b = blockIdx.x, j = threadIdx.x;
  float t = tval[b];
  h0[j] = fmaxf(t * W0[j] + b0[j], 0.f);
  __syncthreads();
  float a = b1[j];
  for (int k = 0; k < Hd; ++k) a += h0[k] * W1[k * Hd + j];
  h1[j] = fmaxf(a, 0.f);
  __syncthreads();
  float c = b2[j];
  for (int k = 0; k < Hd; ++k) c += h1[k] * W2[k * Hd + j];
  tenc[b * Hd + j] = c;
}

__global__ void build_x0_k(const int* __restrict__ batch, const float* __restrict__ tenc,
                           ushort* __restrict__ x0) {
  int idx = blockIdx.x * 256 + threadIdx.x;
  int n = idx >> 9;
  x0[idx] = f2b(tenc[batch[n] * Hd + (idx & 255)]);
}

__global__ void init_small_k(int* __restrict__ cnt1, int* __restrict__ cur1,
                             int* __restrict__ cnt2, int* __restrict__ cur2,
                             float* __restrict__ zerob, float* __restrict__ biascat,
                             const float* __restrict__ gg_bl, const float* __restrict__ gg_br,
                             const float* __restrict__ gf_bl, const float* __restrict__ gf_br) {
  int i = blockIdx.x * 256 + threadIdx.x;
  if (i < NNODE) { cnt1[i] = 0; cur1[i] = 0; cnt2[i] = 0; cur2[i] = 0; return; }
  i -= NNODE;
  if (i < 512) { zerob[i] = 0.f; return; }
  i -= 512;
  if (i < 6144) {
    int layer = i >> 10, c = i & 1023;
    float v;
    if (c < 256)      v = gg_bl[layer * 256 + c];
    else if (c < 512) v = gg_br[layer * 256 + c - 256];
    else if (c < 768) v = gf_bl[layer * 256 + c - 512];
    else              v = gf_br[layer * 256 + c - 768];
    biascat[layer * 1024 + c] = v;
  }
}

// ---------------- fold: WcatT[y][n][k] = sum_j W2[k][j] * Wy[j][n] ----------------
__global__ __launch_bounds__(256) void foldv2_k(
    const float* __restrict__ gg_We, const float* __restrict__ gf_We,
    const float* __restrict__ dec_W0, const float* __restrict__ eeW2,
    const float* __restrict__ eeb2,
    float* __restrict__ Wpart, float* __restrict__ bpart) {
  __shared__ float As[32][68];   // [j][n], padded
  __shared__ float Bt[32][68];   // [j][k], padded
  __shared__ float b2s[32];
  const int tid = threadIdx.x;
  const int bx = blockIdx.x, by = blockIdx.y, bz = blockIdx.z;
  const int y = bx >> 2, n0 = (bx & 3) * 64, k0 = by * 64;
  const int j0 = bz * 32;
  const bool by0 = (by == 0);
  const float* src;
  if (y < 6) src = ((y & 1) == 0 ? gg_We : gf_We) + (size_t)(y >> 1) * 65536;
  else       src = dec_W0 + 1024 * 256;
  if (tid < 32) b2s[tid] = eeb2[j0 + tid];
  {  // stage A tile 32(j) x 64(n), coalesced over n
    int nn = tid & 63, jj0 = tid >> 6;
#pragma unroll
    for (int p = 0; p < 8; ++p)
      As[jj0 + 4 * p][nn] = src[(size_t)(j0 + jj0 + 4 * p) * 256 + n0 + nn];
  }
  {  // stage B tile transposed: W2[k][j] -> Bt[j][k], coalesced over j
    int jj = tid & 31, kk0 = tid >> 5;
#pragma unroll
    for (int p = 0; p < 8; ++p)
      Bt[jj][kk0 + 8 * p] = eeW2[(size_t)(k0 + kk0 + 8 * p) * 256 + j0 + jj];
  }
  __syncthreads();
  const int tn = tid & 15, tk = tid >> 4;
  float acc[4][4];
#pragma unroll
  for (int a = 0; a < 4; ++a)
#pragma unroll
    for (int b = 0; b < 4; ++b) acc[a][b] = 0.f;
  float bacc[4] = {0.f, 0.f, 0.f, 0.f};
#pragma unroll 8
  for (int j = 0; j < 32; ++j) {
    float4 av = *(const float4*)&As[j][tn * 4];
    float4 bv = *(const float4*)&Bt[j][tk * 4];
    if (by0) {
      float eb = b2s[j];
      bacc[0] += eb * av.x; bacc[1] += eb * av.y;
      bacc[2] += eb * av.z; bacc[3] += eb * av.w;
    }
    acc[0][0] += av.x * bv.x; acc[0][1] += av.x * bv.y;
    acc[0][2] += av.x * bv.z; acc[0][3] += av.x * bv.w;
    acc[1][0] += av.y * bv.x; acc[1][1] += av.y * bv.y;
    acc[1][2] += av.y * bv.z; acc[1][3] += av.y * bv.w;
    acc[2][0] += av.z * bv.x; acc[2][1] += av.z * bv.y;
    acc[2][2] += av.z * bv.z; acc[2][3] += av.z * bv.w;
    acc[3][0] += av.w * bv.x; acc[3][1] += av.w * bv.y;
    acc[3][2] += av.w * bv.z; acc[3][3] += av.w * bv.w;
  }
  float* wp = Wpart + (size_t)bz * 458752;
#pragma unroll
  for (int a = 0; a < 4; ++a) {
    int n = n0 + tn * 4 + a;
#pragma unroll
    for (int b = 0; b < 4; ++b)
      wp[((size_t)y * 256 + n) * 256 + k0 + tk * 4 + b] = acc[a][b];
  }
  if (tk == 0 && by0) {
#pragma unroll
    for (int a = 0; a < 4; ++a)
      bpart[(size_t)bz * 1792 + y * 256 + n0 + tn * 4 + a] = bacc[a];
  }
}

// reduce 8 j-chunk partials (ascending bz) -> bf16 WcatT + fp32 bcat
__global__ __launch_bounds__(256) void foldr_k(
    const float* __restrict__ Wpart, const float* __restrict__ bpart,
    const float* __restrict__ dec_b0,
    ushort* __restrict__ WcatT, float* __restrict__ bcat) {
  int idx = blockIdx.x * 256 + threadIdx.x;
  float s = 0.f;
#pragma unroll
  for (int z = 0; z < 8; ++z) s += Wpart[(size_t)z * 458752 + idx];
  WcatT[idx] = f2b(s);
  if (idx < 1792) {
    float b = 0.f;
#pragma unroll
    for (int z = 0; z < 8; ++z) b += bpart[(size_t)z * 1792 + idx];
    if (idx >= 1536) b += dec_b0[idx - 1536];
    bcat[idx] = b;
  }
}

// h0b[i][j] = bf16(relu((i/4096)*W0[j] + b0[j]))   (rank-1, elementwise)
__global__ void build_h0_k(const float* __restrict__ W0, const float* __restrict__ b0,
                           ushort* __restrict__ h0b) {
  int i = blockIdx.x, j = threadIdx.x;
  float a = (float)i / 4096.f;
  h0b[(size_t)i * 256 + j] = f2b(fmaxf(a * W0[j] + b0[j], 0.f));
}

// ---------------- merged weight transposes ----------------
struct TT { const float* src; ushort* dst; int K; int n_off; int ld; int start; };
struct TransArgs { TT t[24]; };

__global__ void trans_all_k(TransArgs a) {
  int b = blockIdx.x;
  int ti = 0;
  while (ti + 1 < 24 && a.t[ti + 1].start <= b) ++ti;
  TT tk = a.t[ti];
  int lb = b - tk.start;
  int gx = tk.K >> 5;
  int k0 = (lb % gx) * 32, n0 = (lb / gx) * 32;
  __shared__ float t[32][33];
  int tx = threadIdx.x & 31, ty = threadIdx.x >> 5;
#pragma unroll
  for (int p = 0; p < 4; ++p)
    t[ty + 8 * p][tx] = tk.src[(size_t)(k0 + ty + 8 * p) * 256 + n0 + tx];
  __syncthreads();
#pragma unroll
  for (int p = 0; p < 4; ++p)
    tk.dst[(size_t)(tk.n_off + n0 + ty + 8 * p) * tk.ld + k0 + tx] = f2b(t[tx][ty + 8 * p]);
}

// ---------------- CSR build (by dst) ----------------

__global__ void deg_all_k(const int* __restrict__ dst1, int* __restrict__ cnt1,
                          const int* __restrict__ dst2, int* __restrict__ cnt2) {
  int e = blockIdx.x * 256 + threadIdx.x;
  if (e < NE1) atomicAdd(cnt1 + dst1[e], 1);
  else if (e - NE1 < NE2) atomicAdd(cnt2 + dst2[e - NE1], 1);
}

__global__ void scan_k(const int* __restrict__ cnt1, int* __restrict__ rs1,
                       const int* __restrict__ cnt2, int* __restrict__ rs2) {
  const int g = blockIdx.x;
  const int* cnt = g ? cnt2 : cnt1;
  int* rowstart = g ? rs2 : rs1;
  const int E = g ? NE2 : NE1;
  __shared__ int part[626];
  int t = threadIdx.x;
  if (t < 625) {
    int s = 0;
#pragma unroll
    for (int i = 0; i < 16; ++i) s += cnt[t * 16 + i];
    part[t] = s;
  }
  __syncthreads();
  if (t == 0) {
    int run = 0;
    for (int i = 0; i < 625; ++i) { int v = part[i]; part[i] = run; run += v; }
  }
  __syncthreads();
  if (t < 625) {
    int off = part[t];
#pragma unroll
    for (int i = 0; i < 16; ++i) { rowstart[t * 16 + i] = off; off += cnt[t * 16 + i]; }
  }
  if (t == 0) rowstart[NNODE] = E;
}

// fill CSR + CSR-ordered side arrays; precompute packed edge records:
// es[].x = src*1024 (xlr row offset in ushorts), es[].y = table_row*TLD
__global__ void fill_all_k(const int* __restrict__ dst1, const int* __restrict__ rs1,
                           int* __restrict__ cur1, int* __restrict__ eid1,
                           const int* __restrict__ src1, const float* __restrict__ eattr1,
                           int2* __restrict__ es1, int* __restrict__ dsts1,
                           const int* __restrict__ dst2, const int* __restrict__ rs2,
                           int* __restrict__ cur2,
                           const int* __restrict__ src2, const float* __restrict__ eattr2,
                           int2* __restrict__ es2) {
  int e = blockIdx.x * 256 + threadIdx.x;
  if (e < NE1) {
    int d = dst1[e];
    int idx = rs1[d] + atomicAdd(cur1 + d, 1);
    eid1[idx] = e;
    int i0 = (int)(eattr1[e] * 4096.f + 0.5f);
    i0 = i0 < 0 ? 0 : (i0 > 4096 ? 4096 : i0);
    es1[idx] = make_int2(src1[e] * 1024, i0 * TLD);
    dsts1[idx] = d;
  } else if (e - NE1 < NE2) {
    int e2 = e - NE1;
    int d = dst2[e2];
    int idx = rs2[d] + atomicAdd(cur2 + d, 1);
    int i0 = (int)(eattr2[e2] * 4096.f + 0.5f);
    i0 = i0 < 0 ? 0 : (i0 > 4096 ? 4096 : i0);
    es2[idx] = make_int2(src2[e2] * 1024, i0 * TLD);
  }
}

// ---------------- fused logit + online-softmax aggregate ----------------
// ONE wave per node, 4 nodes/block; DEPTH-4 software-pipelined gather (4 edges
// in flight via named rotating buffers, 4x unrolled loop -- no arrays, rule #20).
// Each edge's loads issue >= 3 PROCs (~240cy) before use, covering L2 latency.
// Tail: clamped dummy loads; wave-uniform breaks; exact same math order.
__global__ __launch_bounds__(256) void attagg_k(
    const ushort* __restrict__ T, int tcol1, int tcol2,
    const float* __restrict__ att1, const float* __restrict__ att2,
    const ushort* __restrict__ xlr,
    const int2* __restrict__ es1, const int2* __restrict__ es2,
    const int* __restrict__ rs1, const int* __restrict__ rs2,
    const float* __restrict__ bias1, const float* __restrict__ bias2,
    ushort* __restrict__ xnext) {
  __shared__ float att_s[2][256], bias_s[2][256];
  const int tid = threadIdx.x;
  att_s[0][tid] = att1[tid];
  att_s[1][tid] = att2[tid];
  bias_s[0][tid] = bias1[tid];
  bias_s[1][tid] = bias2[tid];
  __syncthreads();
  const int wave = tid >> 6, lane = tid & 63;
  const bool g1 = blockIdx.x < (NNODE / 4);
  const int nid = (g1 ? blockIdx.x : blockIdx.x - NNODE / 4) * 4 + wave;
  const int gi = g1 ? 0 : 1;
  const int2* es = g1 ? es1 : es2;
  const int* rowstart = g1 ? rs1 : rs2;
  const int goff = g1 ? 0 : 512;
  const int colbase = g1 ? 0 : 256;
  const ushort* Tg = T + (g1 ? tcol1 : tcol2);
  const int c = lane * 4;
  ushort4 xr4 = *(const ushort4*)(xlr + (size_t)nid * 1024 + goff + 256 + c);
  const float xr0 = b2f(xr4.x), xr1 = b2f(xr4.y), xr2 = b2f(xr4.z), xr3 = b2f(xr4.w);
  const float a0 = att_s[gi][c], a1 = att_s[gi][c + 1];
  const float a2 = att_s[gi][c + 2], a3 = att_s[gi][c + 3];
  const int s0 = rowstart[nid], s1 = rowstart[nid + 1];
  float m = -1e30f;
  float den = 0.f, ac0 = 0.f, ac1 = 0.f, ac2 = 0.f, ac3 = 0.f;

#define LD1(idx_, xv, lo) { \
    int ix_ = (idx_) < s1 ? (idx_) : (s1 - 1); \
    int2 e_ = es[ix_]; \
    lo = *(const ushort4*)(Tg + e_.y + c); \
    xv = *(const ushort4*)(xlr + e_.x + goff + c); }

#define PROC(xv, lo) { \
    float x0 = b2f(xv.x), x1 = b2f(xv.y), x2 = b2f(xv.z), x3 = b2f(xv.w); \
    float z0 = x0 + xr0 + b2f(lo.x); \
    float z1 = x1 + xr1 + b2f(lo.y); \
    float z2 = x2 + xr2 + b2f(lo.z); \
    float z3 = x3 + xr3 + b2f(lo.w); \
    z0 = fmaxf(z0, 0.2f * z0); \
    z1 = fmaxf(z1, 0.2f * z1); \
    z2 = fmaxf(z2, 0.2f * z2); \
    z3 = fmaxf(z3, 0.2f * z3); \
    float p = z0 * a0 + z1 * a1 + z2 * a2 + z3 * a3; \
    _Pragma("unroll") \
    for (int dd = 1; dd < 64; dd <<= 1) p += __shfl_xor(p, dd); \
    if (p <= m) { \
      float ww = __expf(p - m); \
      den += ww; \
      ac0 += ww * x0; ac1 += ww * x1; ac2 += ww * x2; ac3 += ww * x3; \
    } else { \
      float sc = __expf(m - p); \
      den = den * sc + 1.f; \
      ac0 = ac0 * sc + x0; ac1 = ac1 * sc + x1; \
      ac2 = ac2 * sc + x2; ac3 = ac3 * sc + x3; \
      m = p; \
    } }

  {
    int i = s0;
    if (i < s1) {
      ushort4 xa0, la0, xa1, la1, xa2, la2, xa3, la3;
      LD1(i,     xa0, la0);
      LD1(i + 1, xa1, la1);
      LD1(i + 2, xa2, la2);
      LD1(i + 3, xa3, la3);
      for (;;) {
        PROC(xa0, la0);                       // edge i
        if (i + 1 >= s1) break;
        LD1(i + 4, xa0, la0);
        PROC(xa1, la1);                       // edge i+1
        if (i + 2 >= s1) break;
        LD1(i + 5, xa1, la1);
        PROC(xa2, la2);                       // edge i+2
        if (i + 3 >= s1) break;
        LD1(i + 6, xa2, la2);
        PROC(xa3, la3);                       // edge i+3
        if (i + 4 >= s1) break;
        LD1(i + 7, xa3, la3);
        i += 4;
      }
    }
  }
#undef LD1
#undef PROC
  // direct epilogue: normalize + bias + store (no merge)
  float inv = 1.f / (den + 1e-16f);
  ushort4 o;
  o.x = f2b(ac0 * inv + bias_s[gi][c + 0]);
  o.y = f2b(ac1 * inv + bias_s[gi][c + 1]);
  o.z = f2b(ac2 * inv + bias_s[gi][c + 2]);
  o.w = f2b(ac3 * inv + bias_s[gi][c + 3]);
  *(ushort4*)(xnext + (size_t)nid * 512 + colbase + c) = o;
}

// ---------------- MFMA GEMM: m97 structure (128x128 tile, BK=32, gload_lds) -----
template <bool RELU, bool OBF16>
__global__ __launch_bounds__(256, 4) void mgemm_k(
    const ushort* __restrict__ A, int lda, const ushort* __restrict__ WT, int K,
    const float* __restrict__ bias, void* __restrict__ C, int ldc, int M) {
  __shared__ ushort As[2][128][32];   // 16 KB
  __shared__ ushort Bs[2][128][32];   // 16 KB -> 32 KB total, 4 blocks/CU
  const int tid = threadIdx.x;
  const int wave = tid >> 6, lane = tid & 63;
  const int quad = lane >> 4, l15 = lane & 15;
  const int wr = (wave >> 1) * 64, wc = (wave & 1) * 64;
  const int ncol0 = blockIdx.x * 128;
  const int m0 = blockIdx.y * 128;
  const ushort* WTb = WT + (size_t)ncol0 * K;
  const int srow = wave * 32 + (lane >> 2);
  const int skc = (lane & 3) << 3;
  int ar0 = m0 + srow;      if (ar0 >= M) ar0 = M - 1;
  int ar1 = m0 + srow + 16; if (ar1 >= M) ar1 = M - 1;
  const ushort* Ag0 = A + (size_t)ar0 * lda + skc;
  const ushort* Ag1 = A + (size_t)ar1 * lda + skc;
  const ushort* Bg0 = WTb + (size_t)srow * K + skc;
  const ushort* Bg1 = WTb + (size_t)(srow + 16) * K + skc;
  f32x4 acc[4][4];
#pragma unroll
  for (int i = 0; i < 4; ++i)
#pragma unroll
    for (int j = 0; j < 4; ++j) acc[i][j] = (f32x4){0.f, 0.f, 0.f, 0.f};
  gload16(Ag0, &As[0][wave * 32][0]);
  gload16(Ag1, &As[0][wave * 32 + 16][0]);
  gload16(Bg0, &Bs[0][wave * 32][0]);
  gload16(Bg1, &Bs[0][wave * 32 + 16][0]);
  __syncthreads();
  int cur = 0;
  for (int k0 = 0; k0 < K; k0 += 32) {
    if (k0 + 32 < K) {
      gload16(Ag0 + k0 + 32, &As[cur ^ 1][wave * 32][0]);
      gload16(Ag1 + k0 + 32, &As[cur ^ 1][wave * 32 + 16][0]);
      gload16(Bg0 + k0 + 32, &Bs[cur ^ 1][wave * 32][0]);
      gload16(Bg1 + k0 + 32, &Bs[cur ^ 1][wave * 32 + 16][0]);
    }
    bf16x8 bfr[4];
#pragma unroll
    for (int ni = 0; ni < 4; ++ni)
      bfr[ni] = *(const bf16x8*)&Bs[cur][wc + ni * 16 + l15][quad * 8];
#pragma unroll
    for (int mi = 0; mi < 4; ++mi) {
      bf16x8 af = *(const bf16x8*)&As[cur][wr + mi * 16 + l15][quad * 8];
#pragma unroll
      for (int ni = 0; ni < 4; ++ni) acc[mi][ni] = MFMA16(af, bfr[ni], acc[mi][ni]);
    }
    __syncthreads();
    cur ^= 1;
  }
#pragma unroll
  for (int mi = 0; mi < 4; ++mi)
#pragma unroll
    for (int ni = 0; ni < 4; ++ni) {
      int c = ncol0 + wc + ni * 16 + l15;
      float bv = bias[c];
#pragma unroll
      for (int r = 0; r < 4; ++r) {
        int m = m0 + wr + mi * 16 + quad * 4 + r;
        if (m < M) {
          float v = acc[mi][ni][r] + bv;
          if (RELU) v = fmaxf(v, 0.f);
          if (OBF16) ((ushort*)C)[(size_t)m * ldc + c] = f2b(v);
          else       ((float*)C)[(size_t)m * ldc + c] = v;
        }
      }
    }
}

// ---------------- decoder: dst-ordered tiles, bf16 Z, NN table ----------------
__global__ __launch_bounds__(256, 4) void dec3_k(
    const int2* __restrict__ es1, const ushort* __restrict__ T,
    const ushort* __restrict__ Z, const int* __restrict__ eid,
    const int* __restrict__ dsts1,
    const ushort* __restrict__ W1T, const float* __restrict__ b1,
    const float* __restrict__ W2, const float* __restrict__ b2,
    float* __restrict__ out) {
  __shared__ __align__(16) ushort h0[64][264];   // 33.8 KB; red aliased after phase-2
  float* red = (float*)h0;
  const int tid = threadIdx.x;
  const int wave = tid >> 6, lane = tid & 63;
  const int quad = lane >> 4, l15 = lane & 15;
  const int m0 = blockIdx.x * 64;
  const int arow = tid >> 2;
  {
    int2 ee = es1[m0 + arow];
    int gd = dsts1[m0 + arow];
    const int cq = (tid & 3) * 8;
    const ushort* za = Z + (ee.x >> 1) + cq;            // src*512
    const ushort* zb = Z + (size_t)gd * 512 + 256 + cq;
    const ushort* tz = T + ee.y + 1536 + cq;            // table_row*TLD
    uint4 ra[8], rb[8], rt[8];
#pragma unroll
    for (int s = 0; s < 8; ++s) ra[s] = *(const uint4*)(za + 32 * s);
#pragma unroll
    for (int s = 0; s < 8; ++s) rb[s] = *(const uint4*)(zb + 32 * s);
#pragma unroll
    for (int s = 0; s < 8; ++s) rt[s] = *(const uint4*)(tz + 32 * s);
    __builtin_amdgcn_sched_barrier(0);
#pragma unroll
    for (int s = 0; s < 8; ++s) {
      uint4 o;
      o.x = comb2(ra[s].x, rb[s].x, rt[s].x);
      o.y = comb2(ra[s].y, rb[s].y, rt[s].y);
      o.z = comb2(ra[s].z, rb[s].z, rt[s].z);
      o.w = comb2(ra[s].w, rb[s].w, rt[s].w);
      *(uint4*)&h0[arow][cq + 32 * s] = o;
    }
  }
  __syncthreads();
  f32x4 acc2[4][4];
#pragma unroll
  for (int i = 0; i < 4; ++i)
#pragma unroll
    for (int j = 0; j < 4; ++j) acc2[i][j] = (f32x4){0.f, 0.f, 0.f, 0.f};
  const ushort* wb = W1T + (size_t)(wave * 64 + l15) * 256 + quad * 8;
  bf16x8 bcur[4], bnxt[4];
#pragma unroll
  for (int ni = 0; ni < 4; ++ni)
    bcur[ni] = *(const bf16x8*)(wb + (size_t)(ni * 16) * 256);
#pragma unroll
  for (int k0 = 0; k0 < 256; k0 += 32) {
    if (k0 + 32 < 256) {
#pragma unroll
      for (int ni = 0; ni < 4; ++ni)
        bnxt[ni] = *(const bf16x8*)(wb + (size_t)(ni * 16) * 256 + k0 + 32);
    }
#pragma unroll
    for (int mi = 0; mi < 4; ++mi) {
      bf16x8 af = *(const bf16x8*)&h0[mi * 16 + l15][k0 + quad * 8];
#pragma unroll
      for (int ni = 0; ni < 4; ++ni) acc2[mi][ni] = MFMA16(af, bcur[ni], acc2[mi][ni]);
    }
#pragma unroll
    for (int ni = 0; ni < 4; ++ni) bcur[ni] = bnxt[ni];
  }
  float part[4][4];
#pragma unroll
  for (int mi = 0; mi < 4; ++mi)
#pragma unroll
    for (int r = 0; r < 4; ++r) part[mi][r] = 0.f;
#pragma unroll
  for (int mi = 0; mi < 4; ++mi)
#pragma unroll
    for (int ni = 0; ni < 4; ++ni) {
      int c = wave * 64 + ni * 16 + l15;
      float bv = b1[c], wv = W2[c];
#pragma unroll
      for (int r = 0; r < 4; ++r) {
        float v = fmaxf(acc2[mi][ni][r] + bv, 0.f);
        part[mi][r] += v * wv;
      }
    }
#pragma unroll
  for (int d = 1; d < 16; d <<= 1)
#pragma unroll
    for (int mi = 0; mi < 4; ++mi)
#pragma unroll
      for (int r = 0; r < 4; ++r) part[mi][r] += __shfl_xor(part[mi][r], d);
  __syncthreads();
  if (l15 == 0)
#pragma unroll
    for (int mi = 0; mi < 4; ++mi)
#pragma unroll
      for (int r = 0; r < 4; ++r) red[wave * 64 + mi * 16 + quad * 4 + r] = part[mi][r];
  __syncthreads();
  if (tid < 64) {
    float s = red[tid] + red[64 + tid] + red[128 + tid] + red[192 + tid];
    out[eid[m0 + tid]] = s + b2[0];
  }
}

// ---------------- host ----------------

extern "C" void kernel_launch(void* const* d_in, const int* in_sizes, int n_in,
                              void* d_out, int out_size, void* d_ws, size_t ws_size,
                              hipStream_t stream) {
  const int*   eidx1  = (const int*)d_in[0];
  const float* eattr1 = (const float*)d_in[1];
  const int*   eidx2  = (const int*)d_in[2];
  const float* eattr2 = (const float*)d_in[3];
  const int*   batch  = (const int*)d_in[4];
  const float* tval   = (const float*)d_in[5];
  const float* te_W0 = (const float*)d_in[6];
  const float* te_b0 = (const float*)d_in[7];
  const float* te_W1 = (const float*)d_in[8];
  const float* te_b1 = (const float*)d_in[9];
  const float* te_W2 = (const float*)d_in[10];
  const float* te_b2 = (const float*)d_in[11];
  const float* ee_W0 = (const float*)d_in[12];
  const float* ee_b0 = (const float*)d_in[13];
  const float* ee_W1 = (const float*)d_in[14];
  const float* ee_b1 = (const float*)d_in[15];
  const float* ee_W2 = (const float*)d_in[16];
  const float* ee_b2 = (const float*)d_in[17];
  const float* dec_W0 = (const float*)d_in[18];
  const float* dec_b0 = (const float*)d_in[19];
  const float* dec_W1 = (const float*)d_in[20];
  const float* dec_b1 = (const float*)d_in[21];
  const float* dec_W2 = (const float*)d_in[22];
  const float* dec_b2 = (const float*)d_in[23];
  const float* gg_Wl  = (const float*)d_in[24];
  const float* gg_bl  = (const float*)d_in[25];
  const float* gg_Wr  = (const float*)d_in[26];
  const float* gg_br  = (const float*)d_in[27];
  const float* gg_We  = (const float*)d_in[28];
  const float* gg_att = (const float*)d_in[29];
  const float* gg_bias= (const float*)d_in[30];
  const float* gf_Wl  = (const float*)d_in[31];
  const float* gf_bl  = (const float*)d_in[32];
  const float* gf_Wr  = (const float*)d_in[33];
  const float* gf_br  = (const float*)d_in[34];
  const float* gf_We  = (const float*)d_in[35];
  const float* gf_att = (const float*)d_in[36];
  const float* gf_bias= (const float*)d_in[37];
  (void)in_sizes; (void)n_in; (void)out_size; (void)ws_size;

  const int* src1 = eidx1;
  const int* dst1 = eidx1 + NE1;
  const int* src2 = eidx2;
  const int* dst2 = eidx2 + NE2;

  char* base = (char*)d_ws;
  size_t off = 0;
  auto alloc = [&](size_t bytes) {
    void* p = base + off;
    off += (bytes + 255) & ~(size_t)255;
    return p;
  };
  ushort* x_a    = (ushort*)alloc((size_t)NNODE * 512 * 2);
  ushort* x_b    = (ushort*)alloc((size_t)NNODE * 512 * 2);
  ushort* xlr    = (ushort*)alloc((size_t)NNODE * 1024 * 2);
  ushort* Z      = (ushort*)alloc((size_t)NNODE * 512 * 2);
  ushort* h0b    = (ushort*)alloc((size_t)TROWS * 256 * 2);
  ushort* H1     = (ushort*)alloc((size_t)TROWS * 256 * 2);
  ushort* T      = (ushort*)alloc((size_t)TROWS * TLD * 2);   // 14.7 MB packed tables
  ushort* WcatT  = (ushort*)alloc((size_t)7 * 256 * 256 * 2);
  float*  bcat   = (float*)alloc((size_t)TLD * 4);
  float*  tenc   = (float*)alloc((size_t)16 * Hd * 4);
  ushort* decZT  = (ushort*)alloc((size_t)512 * 512 * 2);
  ushort* decW1T = (ushort*)alloc((size_t)256 * 256 * 2);
  ushort* eeW1T  = (ushort*)alloc((size_t)256 * 256 * 2);
  ushort* wlrT   = (ushort*)alloc((size_t)6 * 512 * 512 * 2);  // [2*i+g]
  float*  biascat= (float*)alloc((size_t)6 * 1024 * 4);
  float*  zerob  = (float*)alloc((size_t)512 * 4);
  int* cnt1      = (int*)alloc((size_t)NNODE * 4);
  int* cur1      = (int*)alloc((size_t)NNODE * 4);
  int* rs1       = (int*)alloc((size_t)(NNODE + 1) * 4);
  int* eid1      = (int*)alloc((size_t)NE1 * 4);
  int2* es1      = (int2*)alloc((size_t)NE1 * 8);
  int* dsts1     = (int*)alloc((size_t)NE1 * 4);
  int* cnt2      = (int*)alloc((size_t)NNODE * 4);
  int* cur2      = (int*)alloc((size_t)NNODE * 4);
  int* rs2       = (int*)alloc((size_t)(NNODE + 1) * 4);
  int2* es2      = (int2*)alloc((size_t)NE2 * 8);

  // fold partials alias T (14.68 MB <= 14.7 MB) and H1 (57 KB <= 2 MB):
  // both are consumed by foldr_k before their real producers (mgemm H1 / mgemm T) run.
  float* Wpart = (float*)T;
  float* bpart = (float*)H1;

  float* out = (float*)d_out;

  // ---- merged setup ----
  init_small_k<<<(NNODE + 512 + 6144 + 255) / 256, 256, 0, stream>>>(
      cnt1, cur1, cnt2, cur2, zerob, biascat, gg_bl, gg_br, gf_bl, gf_br);
  foldv2_k<<<dim3(28, 4, 8), 256, 0, stream>>>(gg_We, gf_We, dec_W0, ee_W2, ee_b2,
                                               Wpart, bpart);
  foldr_k<<<1792, 256, 0, stream>>>(Wpart, bpart, dec_b0, WcatT, bcat);
  build_h0_k<<<TROWS, 256, 0, stream>>>(ee_W0, ee_b0, h0b);

  TransArgs ta;
  int nt = 0, cum = 0;
  auto add = [&](const float* s, ushort* d, int K, int noff, int ld) {
    ta.t[nt].src = s; ta.t[nt].dst = d; ta.t[nt].K = K;
    ta.t[nt].n_off = noff; ta.t[nt].ld = ld; ta.t[nt].start = cum;
    cum += (K / 32) * 8; ++nt;
  };
  add(dec_W1, decW1T, 256, 0, 256);
  add(ee_W1, eeW1T, 256, 0, 256);
  add(dec_W0, decZT, 512, 0, 512);
  add(dec_W0 + 512 * 256, decZT, 512, 256, 512);
  for (int i = 0; i < 3; ++i) {
    add(gg_Wl + (size_t)i * 512 * 256, wlrT + (size_t)(2 * i) * 512 * 512, 512, 0, 512);
    add(gg_Wr + (size_t)i * 512 * 256, wlrT + (size_t)(2 * i) * 512 * 512, 512, 256, 512);
    add(gf_Wl + (size_t)i * 512 * 256, wlrT + (size_t)(2 * i + 1) * 512 * 512, 512, 0, 512);
    add(gf_Wr + (size_t)i * 512 * 256, wlrT + (size_t)(2 * i + 1) * 512 * 512, 512, 256, 512);
  }
  for (int i = nt; i < 24; ++i) ta.t[i].start = 0x7fffffff;
  trans_all_k<<<cum, 256, 0, stream>>>(ta);

  // ---- H1 = relu(h0b @ eeW1T + ee_b1) via MFMA, then table T = H1 @ WcatT + bcat ----
  mgemm_k<true, true><<<dim3(2, (TROWS + 127) / 128), 256, 0, stream>>>(
      h0b, 256, eeW1T, 256, ee_b1, H1, 256, TROWS);
  mgemm_k<false, true><<<dim3(14, (TROWS + 127) / 128), 256, 0, stream>>>(
      H1, 256, WcatT, 256, bcat, T, TLD, TROWS);

  // ---- CSR build ----
  deg_all_k<<<(NE1 + NE2) / 256, 256, 0, stream>>>(dst1, cnt1, dst2, cnt2);
  scan_k<<<2, 640, 0, stream>>>(cnt1, rs1, cnt2, rs2);
  fill_all_k<<<(NE1 + NE2) / 256, 256, 0, stream>>>(
      dst1, rs1, cur1, eid1, src1, eattr1, es1, dsts1,
      dst2, rs2, cur2, src2, eattr2, es2);

  // ---- time encoding -> x0 (bf16) ----
  time_mlp_k<<<16, 256, 0, stream>>>(tval, te_W0, te_b0, te_W1, te_b1, te_W2, te_b2, tenc);
  build_x0_k<<<(NNODE * 512) / 256, 256, 0, stream>>>(batch, tenc, x_a);

  ushort* x_cur = x_a;
  ushort* x_nxt = x_b;
  const int mgrid = (NNODE + 127) / 128;
  for (int i = 0; i < 3; ++i) {
    mgemm_k<false, true><<<dim3(8, mgrid), 256, 0, stream>>>(
        x_cur, 512, wlrT + (size_t)(2 * i) * 512 * 512, 512, biascat + (size_t)i * 1024, xlr, 1024, NNODE);
    attagg_k<<<NNODE / 2, 256, 0, stream>>>(
        T, (2 * i) * 256, (2 * i + 1) * 256,
        gg_att + i * Hd, gf_att + i * Hd, xlr,
        es1, es2, rs1, rs2,
        gg_bias + i * Hd, gf_bias + i * Hd, x_nxt);
    ushort* t = x_cur; x_cur = x_nxt; x_nxt = t;
  }

  // ---- decoder: Z (bf16) per-node, then per-edge fused MLP (dst-ordered tiles) ----
  mgemm_k<false, true><<<dim3(4, mgrid), 256, 0, stream>>>(
      x_cur, 512, decZT, 512, zerob, Z, 512, NNODE);
  dec3_k<<<NE1 / 64, 256, 0, stream>>>(es1, T, Z, eid1, dsts1,
                                       decW1T, dec_b1, dec_W2, dec_b2, out);
}

// Round 15
// 479.767 us; speedup vs baseline: 1.0138x; 1.0138x over previous
//
#include <hip/hip_runtime.h>

#define Hd 256
#define NNODE 10000
#define NE1 131072
#define NE2 65536
#define TROWS 4097
#define TLD 1792     // 7 * 256 packed table columns

typedef __attribute__((ext_vector_type(8))) short bf16x8;
typedef __attribute__((ext_vector_type(4))) float f32x4;

#define MFMA16(a, b, c) __builtin_amdgcn_mfma_f32_16x16x32_bf16((a), (b), (c), 0, 0, 0)

__device__ __forceinline__ float b2f(ushort u) { return __uint_as_float(((unsigned)u) << 16); }
__device__ __forceinline__ ushort f2b(float f) {
  unsigned u = __float_as_uint(f);
  return (ushort)((u + 0x7fffu + ((u >> 16) & 1u)) >> 16);
}

// async global->LDS 16B (dest = wave-uniform base + lane*16; global src per-lane)
__device__ __forceinline__ void gload16(const ushort* g, ushort* l) {
  __builtin_amdgcn_global_load_lds(
      (const __attribute__((address_space(1))) unsigned int*)g,
      (__attribute__((address_space(3))) unsigned int*)l, 16, 0, 0);
}

// combine two packed bf16 lanes: relu(a + b + t), repack (identical math to scalar path)
__device__ __forceinline__ unsigned comb2(unsigned a, unsigned b, unsigned t) {
  float alo = __uint_as_float(a << 16), ahi = __uint_as_float(a & 0xffff0000u);
  float blo = __uint_as_float(b << 16), bhi = __uint_as_float(b & 0xffff0000u);
  float tlo = __uint_as_float(t << 16), thi = __uint_as_float(t & 0xffff0000u);
  float zlo = fmaxf(alo + blo + tlo, 0.f);
  float zhi = fmaxf(ahi + bhi + thi, 0.f);
  return ((unsigned)f2b(zhi) << 16) | (unsigned)f2b(zlo);
}

// ---------------- small kernels ----------------

__global__ void time_mlp_k(const float* __restrict__ tval,
                           const float* __restrict__ W0, const float* __restrict__ b0,
                           const float* __restrict__ W1, const float* __restrict__ b1,
                           const float* __restrict__ W2, const float* __restrict__ b2,
                           float* __restrict__ tenc) {
  __shared__ float h0[Hd], h1[Hd];
  int b = blockIdx.x, j = threadIdx.x;
  float t = tval[b];
  h0[j] = fmaxf(t * W0[j] + b0[j], 0.f);
  __syncthreads();
  float a = b1[j];
  for (int k = 0; k < Hd; ++k) a += h0[k] * W1[k * Hd + j];
  h1[j] = fmaxf(a, 0.f);
  __syncthreads();
  float c = b2[j];
  for (int k = 0; k < Hd; ++k) c += h1[k] * W2[k * Hd + j];
  tenc[b * Hd + j] = c;
}

__global__ void build_x0_k(const int* __restrict__ batch, const float* __restrict__ tenc,
                           ushort* __restrict__ x0) {
  int idx = blockIdx.x * 256 + threadIdx.x;
  int n = idx >> 9;
  x0[idx] = f2b(tenc[batch[n] * Hd + (idx & 255)]);
}

__global__ void init_small_k(int* __restrict__ cnt1, int* __restrict__ cur1,
                             int* __restrict__ cnt2, int* __restrict__ cur2,
                             float* __restrict__ zerob, float* __restrict__ biascat,
                             const float* __restrict__ gg_bl, const float* __restrict__ gg_br,
                             const float* __restrict__ gf_bl, const float* __restrict__ gf_br) {
  int i = blockIdx.x * 256 + threadIdx.x;
  if (i < NNODE) { cnt1[i] = 0; cur1[i] = 0; cnt2[i] = 0; cur2[i] = 0; return; }
  i -= NNODE;
  if (i < 512) { zerob[i] = 0.f; return; }
  i -= 512;
  if (i < 6144) {
    int layer = i >> 10, c = i & 1023;
    float v;
    if (c < 256)      v = gg_bl[layer * 256 + c];
    else if (c < 512) v = gg_br[layer * 256 + c - 256];
    else if (c < 768) v = gf_bl[layer * 256 + c - 512];
    else              v = gf_br[layer * 256 + c - 768];
    biascat[layer * 1024 + c] = v;
  }
}

// ---------------- fold: WcatT[y][n][k] = sum_j W2[k][j] * Wy[j][n] ----------------
// j-split into 8 chunks (grid 28x4x8 = 896 blocks, ~3.5/CU) for TLP; fp32 partials
// to Wpart (aliases T) + bpart (aliases H1); foldr_k sums chunks in ascending order.
__global__ __launch_bounds__(256) void foldv2_k(
    const float* __restrict__ gg_We, const float* __restrict__ gf_We,
    const float* __restrict__ dec_W0, const float* __restrict__ eeW2,
    const float* __restrict__ eeb2,
    float* __restrict__ Wpart, float* __restrict__ bpart) {
  __shared__ float As[32][68];   // [j][n], padded
  __shared__ float Bt[32][68];   // [j][k], padded
  __shared__ float b2s[32];
  const int tid = threadIdx.x;
  const int bx = blockIdx.x, by = blockIdx.y, bz = blockIdx.z;
  const int y = bx >> 2, n0 = (bx & 3) * 64, k0 = by * 64;
  const int j0 = bz * 32;
  const bool by0 = (by == 0);
  const float* src;
  if (y < 6) src = ((y & 1) == 0 ? gg_We : gf_We) + (size_t)(y >> 1) * 65536;
  else       src = dec_W0 + 1024 * 256;
  if (tid < 32) b2s[tid] = eeb2[j0 + tid];
  {  // stage A tile 32(j) x 64(n), coalesced over n
    int nn = tid & 63, jj0 = tid >> 6;
#pragma unroll
    for (int p = 0; p < 8; ++p)
      As[jj0 + 4 * p][nn] = src[(size_t)(j0 + jj0 + 4 * p) * 256 + n0 + nn];
  }
  {  // stage B tile transposed: W2[k][j] -> Bt[j][k], coalesced over j
    int jj = tid & 31, kk0 = tid >> 5;
#pragma unroll
    for (int p = 0; p < 8; ++p)
      Bt[jj][kk0 + 8 * p] = eeW2[(size_t)(k0 + kk0 + 8 * p) * 256 + j0 + jj];
  }
  __syncthreads();
  const int tn = tid & 15, tk = tid >> 4;
  float acc[4][4];
#pragma unroll
  for (int a = 0; a < 4; ++a)
#pragma unroll
    for (int b = 0; b < 4; ++b) acc[a][b] = 0.f;
  float bacc[4] = {0.f, 0.f, 0.f, 0.f};
#pragma unroll 8
  for (int j = 0; j < 32; ++j) {
    float4 av = *(const float4*)&As[j][tn * 4];
    float4 bv = *(const float4*)&Bt[j][tk * 4];
    if (by0) {
      float eb = b2s[j];
      bacc[0] += eb * av.x; bacc[1] += eb * av.y;
      bacc[2] += eb * av.z; bacc[3] += eb * av.w;
    }
    acc[0][0] += av.x * bv.x; acc[0][1] += av.x * bv.y;
    acc[0][2] += av.x * bv.z; acc[0][3] += av.x * bv.w;
    acc[1][0] += av.y * bv.x; acc[1][1] += av.y * bv.y;
    acc[1][2] += av.y * bv.z; acc[1][3] += av.y * bv.w;
    acc[2][0] += av.z * bv.x; acc[2][1] += av.z * bv.y;
    acc[2][2] += av.z * bv.z; acc[2][3] += av.z * bv.w;
    acc[3][0] += av.w * bv.x; acc[3][1] += av.w * bv.y;
    acc[3][2] += av.w * bv.z; acc[3][3] += av.w * bv.w;
  }
  float* wp = Wpart + (size_t)bz * 458752;
#pragma unroll
  for (int a = 0; a < 4; ++a) {
    int n = n0 + tn * 4 + a;
#pragma unroll
    for (int b = 0; b < 4; ++b)
      wp[((size_t)y * 256 + n) * 256 + k0 + tk * 4 + b] = acc[a][b];
  }
  if (tk == 0 && by0) {
#pragma unroll
    for (int a = 0; a < 4; ++a)
      bpart[(size_t)bz * 1792 + y * 256 + n0 + tn * 4 + a] = bacc[a];
  }
}

// reduce 8 j-chunk partials (ascending bz) -> bf16 WcatT + fp32 bcat
__global__ __launch_bounds__(256) void foldr_k(
    const float* __restrict__ Wpart, const float* __restrict__ bpart,
    const float* __restrict__ dec_b0,
    ushort* __restrict__ WcatT, float* __restrict__ bcat) {
  int idx = blockIdx.x * 256 + threadIdx.x;
  float s = 0.f;
#pragma unroll
  for (int z = 0; z < 8; ++z) s += Wpart[(size_t)z * 458752 + idx];
  WcatT[idx] = f2b(s);
  if (idx < 1792) {
    float b = 0.f;
#pragma unroll
    for (int z = 0; z < 8; ++z) b += bpart[(size_t)z * 1792 + idx];
    if (idx >= 1536) b += dec_b0[idx - 1536];
    bcat[idx] = b;
  }
}

// h0b[i][j] = bf16(relu((i/4096)*W0[j] + b0[j]))   (rank-1, elementwise)
__global__ void build_h0_k(const float* __restrict__ W0, const float* __restrict__ b0,
                           ushort* __restrict__ h0b) {
  int i = blockIdx.x, j = threadIdx.x;
  float a = (float)i / 4096.f;
  h0b[(size_t)i * 256 + j] = f2b(fmaxf(a * W0[j] + b0[j], 0.f));
}

// ---------------- merged weight transposes ----------------
struct TT { const float* src; ushort* dst; int K; int n_off; int ld; int start; };
struct TransArgs { TT t[24]; };

__global__ void trans_all_k(TransArgs a) {
  int b = blockIdx.x;
  int ti = 0;
  while (ti + 1 < 24 && a.t[ti + 1].start <= b) ++ti;
  TT tk = a.t[ti];
  int lb = b - tk.start;
  int gx = tk.K >> 5;
  int k0 = (lb % gx) * 32, n0 = (lb / gx) * 32;
  __shared__ float t[32][33];
  int tx = threadIdx.x & 31, ty = threadIdx.x >> 5;
#pragma unroll
  for (int p = 0; p < 4; ++p)
    t[ty + 8 * p][tx] = tk.src[(size_t)(k0 + ty + 8 * p) * 256 + n0 + tx];
  __syncthreads();
#pragma unroll
  for (int p = 0; p < 4; ++p)
    tk.dst[(size_t)(tk.n_off + n0 + ty + 8 * p) * tk.ld + k0 + tx] = f2b(t[tx][ty + 8 * p]);
}

// ---------------- CSR build (by dst) ----------------

__global__ void deg_all_k(const int* __restrict__ dst1, int* __restrict__ cnt1,
                          const int* __restrict__ dst2, int* __restrict__ cnt2) {
  int e = blockIdx.x * 256 + threadIdx.x;
  if (e < NE1) atomicAdd(cnt1 + dst1[e], 1);
  else if (e - NE1 < NE2) atomicAdd(cnt2 + dst2[e - NE1], 1);
}

__global__ void scan_k(const int* __restrict__ cnt1, int* __restrict__ rs1,
                       const int* __restrict__ cnt2, int* __restrict__ rs2) {
  const int g = blockIdx.x;
  const int* cnt = g ? cnt2 : cnt1;
  int* rowstart = g ? rs2 : rs1;
  const int E = g ? NE2 : NE1;
  __shared__ int part[626];
  int t = threadIdx.x;
  if (t < 625) {
    int s = 0;
#pragma unroll
    for (int i = 0; i < 16; ++i) s += cnt[t * 16 + i];
    part[t] = s;
  }
  __syncthreads();
  if (t == 0) {
    int run = 0;
    for (int i = 0; i < 625; ++i) { int v = part[i]; part[i] = run; run += v; }
  }
  __syncthreads();
  if (t < 625) {
    int off = part[t];
#pragma unroll
    for (int i = 0; i < 16; ++i) { rowstart[t * 16 + i] = off; off += cnt[t * 16 + i]; }
  }
  if (t == 0) rowstart[NNODE] = E;
}

// fill CSR + CSR-ordered side arrays; precompute packed edge records:
// es[].x = src*1024 (xlr row offset in ushorts), es[].y = table_row*TLD
__global__ void fill_all_k(const int* __restrict__ dst1, const int* __restrict__ rs1,
                           int* __restrict__ cur1, int* __restrict__ eid1,
                           const int* __restrict__ src1, const float* __restrict__ eattr1,
                           int2* __restrict__ es1, int* __restrict__ dsts1,
                           const int* __restrict__ dst2, const int* __restrict__ rs2,
                           int* __restrict__ cur2,
                           const int* __restrict__ src2, const float* __restrict__ eattr2,
                           int2* __restrict__ es2) {
  int e = blockIdx.x * 256 + threadIdx.x;
  if (e < NE1) {
    int d = dst1[e];
    int idx = rs1[d] + atomicAdd(cur1 + d, 1);
    eid1[idx] = e;
    int i0 = (int)(eattr1[e] * 4096.f + 0.5f);
    i0 = i0 < 0 ? 0 : (i0 > 4096 ? 4096 : i0);
    es1[idx] = make_int2(src1[e] * 1024, i0 * TLD);
    dsts1[idx] = d;
  } else if (e - NE1 < NE2) {
    int e2 = e - NE1;
    int d = dst2[e2];
    int idx = rs2[d] + atomicAdd(cur2 + d, 1);
    int i0 = (int)(eattr2[e2] * 4096.f + 0.5f);
    i0 = i0 < 0 ? 0 : (i0 > 4096 ? 4096 : i0);
    es2[idx] = make_int2(src2[e2] * 1024, i0 * TLD);
  }
}

// ---------------- fused logit + online-softmax aggregate ----------------
// ONE wave per node, 4 nodes/block; depth-2 stride-1 pipelined gather; packed
// int2 edge records; wave-uniform fast-path online softmax (exact, 1 exp/edge).
__global__ __launch_bounds__(256) void attagg_k(
    const ushort* __restrict__ T, int tcol1, int tcol2,
    const float* __restrict__ att1, const float* __restrict__ att2,
    const ushort* __restrict__ xlr,
    const int2* __restrict__ es1, const int2* __restrict__ es2,
    const int* __restrict__ rs1, const int* __restrict__ rs2,
    const float* __restrict__ bias1, const float* __restrict__ bias2,
    ushort* __restrict__ xnext) {
  __shared__ float att_s[2][256], bias_s[2][256];
  const int tid = threadIdx.x;
  att_s[0][tid] = att1[tid];
  att_s[1][tid] = att2[tid];
  bias_s[0][tid] = bias1[tid];
  bias_s[1][tid] = bias2[tid];
  __syncthreads();
  const int wave = tid >> 6, lane = tid & 63;
  const bool g1 = blockIdx.x < (NNODE / 4);
  const int nid = (g1 ? blockIdx.x : blockIdx.x - NNODE / 4) * 4 + wave;
  const int gi = g1 ? 0 : 1;
  const int2* es = g1 ? es1 : es2;
  const int* rowstart = g1 ? rs1 : rs2;
  const int goff = g1 ? 0 : 512;
  const int colbase = g1 ? 0 : 256;
  const ushort* Tg = T + (g1 ? tcol1 : tcol2);
  const int c = lane * 4;
  ushort4 xr4 = *(const ushort4*)(xlr + (size_t)nid * 1024 + goff + 256 + c);
  const float xr0 = b2f(xr4.x), xr1 = b2f(xr4.y), xr2 = b2f(xr4.z), xr3 = b2f(xr4.w);
  const float a0 = att_s[gi][c], a1 = att_s[gi][c + 1];
  const float a2 = att_s[gi][c + 2], a3 = att_s[gi][c + 3];
  const int s0 = rowstart[nid], s1 = rowstart[nid + 1];
  float m = -1e30f;
  float den = 0.f, ac0 = 0.f, ac1 = 0.f, ac2 = 0.f, ac3 = 0.f;
  {
    int i = s0;
    if (i < s1) {
      ushort4 xv0, lo0;
      ushort4 xv1 = {0, 0, 0, 0}, lo1 = {0, 0, 0, 0};
      {  // prologue edge i
        int2 e0 = es[i];
        lo0 = *(const ushort4*)(Tg + e0.y + c);
        xv0 = *(const ushort4*)(xlr + e0.x + goff + c);
      }
      if (i + 1 < s1) {  // prologue edge i+1
        int2 e1 = es[i + 1];
        lo1 = *(const ushort4*)(Tg + e1.y + c);
        xv1 = *(const ushort4*)(xlr + e1.x + goff + c);
      }
      for (; i < s1; ++i) {
        ushort4 xv_c = xv0, lo_c = lo0;
        xv0 = xv1; lo0 = lo1;
        if (i + 2 < s1) {  // prefetch 2 edges ahead
          int2 en = es[i + 2];
          lo1 = *(const ushort4*)(Tg + en.y + c);
          xv1 = *(const ushort4*)(xlr + en.x + goff + c);
        }
        float x0 = b2f(xv_c.x), x1 = b2f(xv_c.y), x2 = b2f(xv_c.z), x3 = b2f(xv_c.w);
        float z0 = x0 + xr0 + b2f(lo_c.x);
        float z1 = x1 + xr1 + b2f(lo_c.y);
        float z2 = x2 + xr2 + b2f(lo_c.z);
        float z3 = x3 + xr3 + b2f(lo_c.w);
        z0 = fmaxf(z0, 0.2f * z0);
        z1 = fmaxf(z1, 0.2f * z1);
        z2 = fmaxf(z2, 0.2f * z2);
        z3 = fmaxf(z3, 0.2f * z3);
        float p = z0 * a0 + z1 * a1 + z2 * a2 + z3 * a3;
#pragma unroll
        for (int dd = 1; dd < 64; dd <<= 1) p += __shfl_xor(p, dd);
        if (p <= m) {          // wave-uniform: no new max, sc == 1 exactly
          float ww = __expf(p - m);
          den += ww;
          ac0 += ww * x0;
          ac1 += ww * x1;
          ac2 += ww * x2;
          ac3 += ww * x3;
        } else {               // new max: ww == exp(p-p) == 1 exactly
          float sc = __expf(m - p);
          den = den * sc + 1.f;
          ac0 = ac0 * sc + x0;
          ac1 = ac1 * sc + x1;
          ac2 = ac2 * sc + x2;
          ac3 = ac3 * sc + x3;
          m = p;
        }
      }
    }
  }
  // direct epilogue: normalize + bias + store (no merge)
  float inv = 1.f / (den + 1e-16f);
  ushort4 o;
  o.x = f2b(ac0 * inv + bias_s[gi][c + 0]);
  o.y = f2b(ac1 * inv + bias_s[gi][c + 1]);
  o.z = f2b(ac2 * inv + bias_s[gi][c + 2]);
  o.w = f2b(ac3 * inv + bias_s[gi][c + 3]);
  *(ushort4*)(xnext + (size_t)nid * 512 + colbase + c) = o;
}

// ---------------- MFMA GEMM: m97 structure (128x128 tile, BK=32, gload_lds) -----
// 4 waves, each a 64x64 quadrant (acc[4][4]); linear [128][32] LDS; double-
// buffered, 1 barrier/K-step. Grid: x = N/128 (fast), y = M-blocks.
template <bool RELU, bool OBF16>
__global__ __launch_bounds__(256, 4) void mgemm_k(
    const ushort* __restrict__ A, int lda, const ushort* __restrict__ WT, int K,
    const float* __restrict__ bias, void* __restrict__ C, int ldc, int M) {
  __shared__ ushort As[2][128][32];   // 16 KB
  __shared__ ushort Bs[2][128][32];   // 16 KB -> 32 KB total, 4 blocks/CU
  const int tid = threadIdx.x;
  const int wave = tid >> 6, lane = tid & 63;
  const int quad = lane >> 4, l15 = lane & 15;
  const int wr = (wave >> 1) * 64, wc = (wave & 1) * 64;
  const int ncol0 = blockIdx.x * 128;
  const int m0 = blockIdx.y * 128;
  const ushort* WTb = WT + (size_t)ncol0 * K;
  const int srow = wave * 32 + (lane >> 2);
  const int skc = (lane & 3) << 3;
  int ar0 = m0 + srow;      if (ar0 >= M) ar0 = M - 1;
  int ar1 = m0 + srow + 16; if (ar1 >= M) ar1 = M - 1;
  const ushort* Ag0 = A + (size_t)ar0 * lda + skc;
  const ushort* Ag1 = A + (size_t)ar1 * lda + skc;
  const ushort* Bg0 = WTb + (size_t)srow * K + skc;
  const ushort* Bg1 = WTb + (size_t)(srow + 16) * K + skc;
  f32x4 acc[4][4];
#pragma unroll
  for (int i = 0; i < 4; ++i)
#pragma unroll
    for (int j = 0; j < 4; ++j) acc[i][j] = (f32x4){0.f, 0.f, 0.f, 0.f};
  gload16(Ag0, &As[0][wave * 32][0]);
  gload16(Ag1, &As[0][wave * 32 + 16][0]);
  gload16(Bg0, &Bs[0][wave * 32][0]);
  gload16(Bg1, &Bs[0][wave * 32 + 16][0]);
  __syncthreads();
  int cur = 0;
  for (int k0 = 0; k0 < K; k0 += 32) {
    if (k0 + 32 < K) {
      gload16(Ag0 + k0 + 32, &As[cur ^ 1][wave * 32][0]);
      gload16(Ag1 + k0 + 32, &As[cur ^ 1][wave * 32 + 16][0]);
      gload16(Bg0 + k0 + 32, &Bs[cur ^ 1][wave * 32][0]);
      gload16(Bg1 + k0 + 32, &Bs[cur ^ 1][wave * 32 + 16][0]);
    }
    bf16x8 bfr[4];
#pragma unroll
    for (int ni = 0; ni < 4; ++ni)
      bfr[ni] = *(const bf16x8*)&Bs[cur][wc + ni * 16 + l15][quad * 8];
#pragma unroll
    for (int mi = 0; mi < 4; ++mi) {
      bf16x8 af = *(const bf16x8*)&As[cur][wr + mi * 16 + l15][quad * 8];
#pragma unroll
      for (int ni = 0; ni < 4; ++ni) acc[mi][ni] = MFMA16(af, bfr[ni], acc[mi][ni]);
    }
    __syncthreads();
    cur ^= 1;
  }
#pragma unroll
  for (int mi = 0; mi < 4; ++mi)
#pragma unroll
    for (int ni = 0; ni < 4; ++ni) {
      int c = ncol0 + wc + ni * 16 + l15;
      float bv = bias[c];
#pragma unroll
      for (int r = 0; r < 4; ++r) {
        int m = m0 + wr + mi * 16 + quad * 4 + r;
        if (m < M) {
          float v = acc[mi][ni][r] + bv;
          if (RELU) v = fmaxf(v, 0.f);
          if (OBF16) ((ushort*)C)[(size_t)m * ldc + c] = f2b(v);
          else       ((float*)C)[(size_t)m * ldc + c] = v;
        }
      }
    }
}

// ---------------- decoder: dst-ordered tiles, bf16 Z, NN table ----------------
// phase-1: gather batch pinned via sched_group_barrier pipeline spec (VMEM_READ
// x24 then VALU then DS_WRITE; best-measured build, kept verbatim).
__global__ __launch_bounds__(256, 4) void dec3_k(
    const int2* __restrict__ es1, const ushort* __restrict__ T,
    const ushort* __restrict__ Z, const int* __restrict__ eid,
    const int* __restrict__ dsts1,
    const ushort* __restrict__ W1T, const float* __restrict__ b1,
    const float* __restrict__ W2, const float* __restrict__ b2,
    float* __restrict__ out) {
  __shared__ __align__(16) ushort h0[64][264];   // 33.8 KB; red aliased after phase-2
  float* red = (float*)h0;
  const int tid = threadIdx.x;
  const int wave = tid >> 6, lane = tid & 63;
  const int quad = lane >> 4, l15 = lane & 15;
  const int m0 = blockIdx.x * 64;
  const int arow = tid >> 2;
  {
    int2 ee = es1[m0 + arow];
    int gd = dsts1[m0 + arow];
    const int cq = (tid & 3) * 8;
    const ushort* za = Z + (ee.x >> 1) + cq;            // src*512
    const ushort* zb = Z + (size_t)gd * 512 + 256 + cq;
    const ushort* tz = T + ee.y + 1536 + cq;            // table_row*TLD
    uint4 ra[8], rb[8], rt[8];
#pragma unroll
    for (int s = 0; s < 8; ++s) ra[s] = *(const uint4*)(za + 32 * s);
#pragma unroll
    for (int s = 0; s < 8; ++s) rb[s] = *(const uint4*)(zb + 32 * s);
#pragma unroll
    for (int s = 0; s < 8; ++s) rt[s] = *(const uint4*)(tz + 32 * s);
    // pipeline spec: all 24 vmem reads issue before any combine VALU
    __builtin_amdgcn_sched_group_barrier(0x020, 24, 0);  // VMEM_READ x24
    __builtin_amdgcn_sched_group_barrier(0x002, 200, 0); // VALU (combine)
    __builtin_amdgcn_sched_group_barrier(0x200, 8, 0);   // DS_WRITE x8
#pragma unroll
    for (int s = 0; s < 8; ++s) {
      uint4 o;
      o.x = comb2(ra[s].x, rb[s].x, rt[s].x);
      o.y = comb2(ra[s].y, rb[s].y, rt[s].y);
      o.z = comb2(ra[s].z, rb[s].z, rt[s].z);
      o.w = comb2(ra[s].w, rb[s].w, rt[s].w);
      *(uint4*)&h0[arow][cq + 32 * s] = o;
    }
  }
  __syncthreads();
  f32x4 acc2[4][4];
#pragma unroll
  for (int i = 0; i < 4; ++i)
#pragma unroll
    for (int j = 0; j < 4; ++j) acc2[i][j] = (f32x4){0.f, 0.f, 0.f, 0.f};
  const ushort* wb = W1T + (size_t)(wave * 64 + l15) * 256 + quad * 8;
  bf16x8 bcur[4], bnxt[4];
#pragma unroll
  for (int ni = 0; ni < 4; ++ni)
    bcur[ni] = *(const bf16x8*)(wb + (size_t)(ni * 16) * 256);
#pragma unroll
  for (int k0 = 0; k0 < 256; k0 += 32) {
    if (k0 + 32 < 256) {
#pragma unroll
      for (int ni = 0; ni < 4; ++ni)
        bnxt[ni] = *(const bf16x8*)(wb + (size_t)(ni * 16) * 256 + k0 + 32);
    }
#pragma unroll
    for (int mi = 0; mi < 4; ++mi) {
      bf16x8 af = *(const bf16x8*)&h0[mi * 16 + l15][k0 + quad * 8];
#pragma unroll
      for (int ni = 0; ni < 4; ++ni) acc2[mi][ni] = MFMA16(af, bcur[ni], acc2[mi][ni]);
    }
#pragma unroll
    for (int ni = 0; ni < 4; ++ni) bcur[ni] = bnxt[ni];
  }
  float part[4][4];
#pragma unroll
  for (int mi = 0; mi < 4; ++mi)
#pragma unroll
    for (int r = 0; r < 4; ++r) part[mi][r] = 0.f;
#pragma unroll
  for (int mi = 0; mi < 4; ++mi)
#pragma unroll
    for (int ni = 0; ni < 4; ++ni) {
      int c = wave * 64 + ni * 16 + l15;
      float bv = b1[c], wv = W2[c];
#pragma unroll
      for (int r = 0; r < 4; ++r) {
        float v = fmaxf(acc2[mi][ni][r] + bv, 0.f);
        part[mi][r] += v * wv;
      }
    }
#pragma unroll
  for (int d = 1; d < 16; d <<= 1)
#pragma unroll
    for (int mi = 0; mi < 4; ++mi)
#pragma unroll
      for (int r = 0; r < 4; ++r) part[mi][r] += __shfl_xor(part[mi][r], d);
  __syncthreads();
  if (l15 == 0)
#pragma unroll
    for (int mi = 0; mi < 4; ++mi)
#pragma unroll
      for (int r = 0; r < 4; ++r) red[wave * 64 + mi * 16 + quad * 4 + r] = part[mi][r];
  __syncthreads();
  if (tid < 64) {
    float s = red[tid] + red[64 + tid] + red[128 + tid] + red[192 + tid];
    out[eid[m0 + tid]] = s + b2[0];
  }
}

// ---------------- host ----------------

extern "C" void kernel_launch(void* const* d_in, const int* in_sizes, int n_in,
                              void* d_out, int out_size, void* d_ws, size_t ws_size,
                              hipStream_t stream) {
  const int*   eidx1  = (const int*)d_in[0];
  const float* eattr1 = (const float*)d_in[1];
  const int*   eidx2  = (const int*)d_in[2];
  const float* eattr2 = (const float*)d_in[3];
  const int*   batch  = (const int*)d_in[4];
  const float* tval   = (const float*)d_in[5];
  const float* te_W0 = (const float*)d_in[6];
  const float* te_b0 = (const float*)d_in[7];
  const float* te_W1 = (const float*)d_in[8];
  const float* te_b1 = (const float*)d_in[9];
  const float* te_W2 = (const float*)d_in[10];
  const float* te_b2 = (const float*)d_in[11];
  const float* ee_W0 = (const float*)d_in[12];
  const float* ee_b0 = (const float*)d_in[13];
  const float* ee_W1 = (const float*)d_in[14];
  const float* ee_b1 = (const float*)d_in[15];
  const float* ee_W2 = (const float*)d_in[16];
  const float* ee_b2 = (const float*)d_in[17];
  const float* dec_W0 = (const float*)d_in[18];
  const float* dec_b0 = (const float*)d_in[19];
  const float* dec_W1 = (const float*)d_in[20];
  const float* dec_b1 = (const float*)d_in[21];
  const float* dec_W2 = (const float*)d_in[22];
  const float* dec_b2 = (const float*)d_in[23];
  const float* gg_Wl  = (const float*)d_in[24];
  const float* gg_bl  = (const float*)d_in[25];
  const float* gg_Wr  = (const float*)d_in[26];
  const float* gg_br  = (const float*)d_in[27];
  const float* gg_We  = (const float*)d_in[28];
  const float* gg_att = (const float*)d_in[29];
  const float* gg_bias= (const float*)d_in[30];
  const float* gf_Wl  = (const float*)d_in[31];
  const float* gf_bl  = (const float*)d_in[32];
  const float* gf_Wr  = (const float*)d_in[33];
  const float* gf_br  = (const float*)d_in[34];
  const float* gf_We  = (const float*)d_in[35];
  const float* gf_att = (const float*)d_in[36];
  const float* gf_bias= (const float*)d_in[37];
  (void)in_sizes; (void)n_in; (void)out_size; (void)ws_size;

  const int* src1 = eidx1;
  const int* dst1 = eidx1 + NE1;
  const int* src2 = eidx2;
  const int* dst2 = eidx2 + NE2;

  char* base = (char*)d_ws;
  size_t off = 0;
  auto alloc = [&](size_t bytes) {
    void* p = base + off;
    off += (bytes + 255) & ~(size_t)255;
    return p;
  };
  ushort* x_a    = (ushort*)alloc((size_t)NNODE * 512 * 2);
  ushort* x_b    = (ushort*)alloc((size_t)NNODE * 512 * 2);
  ushort* xlr    = (ushort*)alloc((size_t)NNODE * 1024 * 2);
  ushort* Z      = (ushort*)alloc((size_t)NNODE * 512 * 2);
  ushort* h0b    = (ushort*)alloc((size_t)TROWS * 256 * 2);
  ushort* H1     = (ushort*)alloc((size_t)TROWS * 256 * 2);
  ushort* T      = (ushort*)alloc((size_t)TROWS * TLD * 2);   // 14.7 MB packed tables
  ushort* WcatT  = (ushort*)alloc((size_t)7 * 256 * 256 * 2);
  float*  bcat   = (float*)alloc((size_t)TLD * 4);
  float*  tenc   = (float*)alloc((size_t)16 * Hd * 4);
  ushort* decZT  = (ushort*)alloc((size_t)512 * 512 * 2);
  ushort* decW1T = (ushort*)alloc((size_t)256 * 256 * 2);
  ushort* eeW1T  = (ushort*)alloc((size_t)256 * 256 * 2);
  ushort* wlrT   = (ushort*)alloc((size_t)6 * 512 * 512 * 2);  // [2*i+g]
  float*  biascat= (float*)alloc((size_t)6 * 1024 * 4);
  float*  zerob  = (float*)alloc((size_t)512 * 4);
  int* cnt1      = (int*)alloc((size_t)NNODE * 4);
  int* cur1      = (int*)alloc((size_t)NNODE * 4);
  int* rs1       = (int*)alloc((size_t)(NNODE + 1) * 4);
  int* eid1      = (int*)alloc((size_t)NE1 * 4);
  int2* es1      = (int2*)alloc((size_t)NE1 * 8);
  int* dsts1     = (int*)alloc((size_t)NE1 * 4);
  int* cnt2      = (int*)alloc((size_t)NNODE * 4);
  int* cur2      = (int*)alloc((size_t)NNODE * 4);
  int* rs2       = (int*)alloc((size_t)(NNODE + 1) * 4);
  int2* es2      = (int2*)alloc((size_t)NE2 * 8);

  // fold partials alias T (14.68 MB <= 14.7 MB) and H1 (57 KB <= 2 MB):
  // both are consumed by foldr_k before their real producers (mgemm H1 / mgemm T) run.
  float* Wpart = (float*)T;
  float* bpart = (float*)H1;

  float* out = (float*)d_out;

  // ---- merged setup ----
  init_small_k<<<(NNODE + 512 + 6144 + 255) / 256, 256, 0, stream>>>(
      cnt1, cur1, cnt2, cur2, zerob, biascat, gg_bl, gg_br, gf_bl, gf_br);
  foldv2_k<<<dim3(28, 4, 8), 256, 0, stream>>>(gg_We, gf_We, dec_W0, ee_W2, ee_b2,
                                               Wpart, bpart);
  foldr_k<<<1792, 256, 0, stream>>>(Wpart, bpart, dec_b0, WcatT, bcat);
  build_h0_k<<<TROWS, 256, 0, stream>>>(ee_W0, ee_b0, h0b);

  TransArgs ta;
  int nt = 0, cum = 0;
  auto add = [&](const float* s, ushort* d, int K, int noff, int ld) {
    ta.t[nt].src = s; ta.t[nt].dst = d; ta.t[nt].K = K;
    ta.t[nt].n_off = noff; ta.t[nt].ld = ld; ta.t[nt].start = cum;
    cum += (K / 32) * 8; ++nt;
  };
  add(dec_W1, decW1T, 256, 0, 256);
  add(ee_W1, eeW1T, 256, 0, 256);
  add(dec_W0, decZT, 512, 0, 512);
  add(dec_W0 + 512 * 256, decZT, 512, 256, 512);
  for (int i = 0; i < 3; ++i) {
    add(gg_Wl + (size_t)i * 512 * 256, wlrT + (size_t)(2 * i) * 512 * 512, 512, 0, 512);
    add(gg_Wr + (size_t)i * 512 * 256, wlrT + (size_t)(2 * i) * 512 * 512, 512, 256, 512);
    add(gf_Wl + (size_t)i * 512 * 256, wlrT + (size_t)(2 * i + 1) * 512 * 512, 512, 0, 512);
    add(gf_Wr + (size_t)i * 512 * 256, wlrT + (size_t)(2 * i + 1) * 512 * 512, 512, 256, 512);
  }
  for (int i = nt; i < 24; ++i) ta.t[i].start = 0x7fffffff;
  trans_all_k<<<cum, 256, 0, stream>>>(ta);

  // ---- H1 = relu(h0b @ eeW1T + ee_b1) via MFMA, then table T = H1 @ WcatT + bcat ----
  mgemm_k<true, true><<<dim3(2, (TROWS + 127) / 128), 256, 0, stream>>>(
      h0b, 256, eeW1T, 256, ee_b1, H1, 256, TROWS);
  mgemm_k<false, true><<<dim3(14, (TROWS + 127) / 128), 256, 0, stream>>>(
      H1, 256, WcatT, 256, bcat, T, TLD, TROWS);

  // ---- CSR build ----
  deg_all_k<<<(NE1 + NE2) / 256, 256, 0, stream>>>(dst1, cnt1, dst2, cnt2);
  scan_k<<<2, 640, 0, stream>>>(cnt1, rs1, cnt2, rs2);
  fill_all_k<<<(NE1 + NE2) / 256, 256, 0, stream>>>(
      dst1, rs1, cur1, eid1, src1, eattr1, es1, dsts1,
      dst2, rs2, cur2, src2, eattr2, es2);

  // ---- time encoding -> x0 (bf16) ----
  time_mlp_k<<<16, 256, 0, stream>>>(tval, te_W0, te_b0, te_W1, te_b1, te_W2, te_b2, tenc);
  build_x0_k<<<(NNODE * 512) / 256, 256, 0, stream>>>(batch, tenc, x_a);

  ushort* x_cur = x_a;
  ushort* x_nxt = x_b;
  const int mgrid = (NNODE + 127) / 128;
  for (int i = 0; i < 3; ++i) {
    mgemm_k<false, true><<<dim3(8, mgrid), 256, 0, stream>>>(
        x_cur, 512, wlrT + (size_t)(2 * i) * 512 * 512, 512, biascat + (size_t)i * 1024, xlr, 1024, NNODE);
    attagg_k<<<NNODE / 2, 256, 0, stream>>>(
        T, (2 * i) * 256, (2 * i + 1) * 256,
        gg_att + i * Hd, gf_att + i * Hd, xlr,
        es1, es2, rs1, rs2,
        gg_bias + i * Hd, gf_bias + i * Hd, x_nxt);
    ushort* t = x_cur; x_cur = x_nxt; x_nxt = t;
  }

  // ---- decoder: Z (bf16) per-node, then per-edge fused MLP (dst-ordered tiles) ----
  mgemm_k<false, true><<<dim3(4, mgrid), 256, 0, stream>>>(
      x_cur, 512, decZT, 512, zerob, Z, 512, NNODE);
  dec3_k<<<NE1 / 64, 256, 0, stream>>>(es1, T, Z, eid1, dsts1,
                                       decW1T, dec_b1, dec_W2, dec_b2, out);
}